// Round 7
// baseline (290.283 us; speedup 1.0000x reference)
//
#include <hip/hip_runtime.h>
#include <hip/hip_bf16.h>
#include <math.h>

// Problem constants
#define NNODES 10000
#define NEDGE  160000
// MULT=16, NL=2, DIM=4, EDGE_DIM=32, HID=128, RANK=8, H=4, HM=4

typedef unsigned short u16;
using bf16x8 = __attribute__((ext_vector_type(8))) short;
using u16x8  = __attribute__((ext_vector_type(8))) unsigned short;
using f32x4  = __attribute__((ext_vector_type(4))) float;

static __device__ __forceinline__ u16 f2bf(float x) {
  unsigned u = __float_as_uint(x);
  u += 0x7FFFu + ((u >> 16) & 1u);     // RNE
  return (u16)(u >> 16);
}
static __device__ __forceinline__ float bf2f(u16 h) {
  return __uint_as_float(((unsigned)h) << 16);
}
// packed RNE f32x2 -> bf16x2 (gfx950 v_cvt_pk_bf16_f32 via HIP API)
static __device__ __forceinline__ unsigned pack_bf16(float a, float b) {
  __hip_bfloat162 h = __float22bfloat162_rn(make_float2(a, b));
  return *(unsigned*)&h;               // low = a, high = b
}
// tanh-form gelu: x*sigmoid(x*(1.5957691 + 0.0713548*x^2)); |err| < 5e-4 abs.
static __device__ __forceinline__ float fast_gelu(float x) {
  float y = x * __builtin_fmaf(0.07135481283f, x * x, 1.5957691216f);
  float e = __expf(y);
  return x - x * __builtin_amdgcn_rcpf(e + 1.0f);
}
// sum over 16-lane groups, pure DPP (no DS pipe): xor1,xor2 quad_perm;
// half-mirror (xor7), mirror (xor15) -> group closure = all 16 lanes.
static __device__ __forceinline__ float dpp_red16(float p) {
  p += __int_as_float(__builtin_amdgcn_update_dpp(0, __float_as_int(p), 0xB1,  0xF, 0xF, true));
  p += __int_as_float(__builtin_amdgcn_update_dpp(0, __float_as_int(p), 0x4E,  0xF, 0xF, true));
  p += __int_as_float(__builtin_amdgcn_update_dpp(0, __float_as_int(p), 0x141, 0xF, 0xF, true));
  p += __int_as_float(__builtin_amdgcn_update_dpp(0, __float_as_int(p), 0x140, 0xF, 0xF, true));
  return p;
}

// ---------------- fused setup: csr_zero | prep_w | prep_w1 | q --------------
// Wsw element at ((tg*4+ks)*64 + lane)*8 + j  ==  W[k][col],
//   k = ks*32 + (lane>>4)*8 + j, col = tg*16 + (lane&15).
__global__ void __launch_bounds__(256) setup_kernel(
    const float* __restrict__ kwr, const float* __restrict__ kwl,
    const float* __restrict__ vwr, const float* __restrict__ vwl,
    u16* __restrict__ Wsw,
    const float* __restrict__ kw1, const float* __restrict__ vw1,
    u16* __restrict__ W1sw,
    const float* __restrict__ f, const float* __restrict__ qw,
    const float* __restrict__ qb, float* __restrict__ q,
    int* __restrict__ cnt) {
  int b = blockIdx.x, tid = threadIdx.x;
  if (b < 40) {                       // csr_zero
    int i = b * 256 + tid;
    if (i < NNODES) cnt[i] = 0;
  } else if (b < 552) {               // prep_w: 512 blocks
    int idx = (b - 40) * 256 + tid;   // 0..131071  (4 slots x 32768)
    int slot = idx >> 15;
    int w = idx & 32767;
    int j = w & 7, lane = (w >> 3) & 63, ks = (w >> 9) & 3, tg = w >> 11;
    int k   = ks * 32 + ((lane >> 4) << 3) + j;
    int col = (tg << 4) + (lane & 15);
    const float* s = (slot == 0) ? kwr : (slot == 1) ? kwl : (slot == 2) ? vwr : vwl;
    Wsw[idx] = f2bf(s[k * 256 + col]);
  } else if (b < 584) {               // prep_w1: 32 blocks
    int idx = (b - 552) * 256 + tid;  // 0..8191 (2 slots x 4096)
    int slot = idx >> 12;
    int w = idx & 4095;
    int j = w & 7, lane = (w >> 3) & 63, nt = w >> 9;
    int k   = ((lane >> 4) << 3) + j;
    int col = (nt << 4) + (lane & 15);
    const float* s = (slot == 0) ? kw1 : vw1;
    W1sw[idx] = f2bf(s[k * 128 + col]);
  } else {                            // q: 625 blocks
    int i = (b - 584) * 256 + tid;    // n*16 + o
    if (i >= NNODES * 16) return;
    int n = i >> 4, o = i & 15;
    const float* frow = f + (size_t)n * 64;
    float o0 = 0.f, o1 = 0.f, o2 = 0.f, o3 = 0.f;
#pragma unroll
    for (int m = 0; m < 16; ++m) {
      float w0 = qw[o * 16 + m];
      float w1 = qw[(16 + o) * 16 + m];
      o0 += w0 * frow[m * 4 + 0];
      o1 += w1 * frow[m * 4 + 1];
      o2 += w1 * frow[m * 4 + 2];
      o3 += w1 * frow[m * 4 + 3];
    }
    o0 += qb[o];
    float4 r = make_float4(o0, o1, o2, o3);
    *(float4*)(q + (size_t)i * 4) = r;
  }
}

// ---------------- CSR build ---------------------------------------------------
__global__ void csr_count_kernel(const int* __restrict__ dst, int* __restrict__ cnt) {
  int e = blockIdx.x * 256 + threadIdx.x;        // grid exact
  atomicAdd(&cnt[dst[e]], 1);
}
__global__ void __launch_bounds__(1024) csr_scan_kernel(
    const int* __restrict__ cnt, int* __restrict__ rowptr, int* __restrict__ cursor) {
  __shared__ int part[1024];
  int t = threadIdx.x;
  int base = t * 10;                              // 1024*10 = 10240 >= NNODES
  int s = 0;
#pragma unroll
  for (int i = 0; i < 10; ++i) { int idx = base + i; if (idx < NNODES) s += cnt[idx]; }
  part[t] = s;
  __syncthreads();
  for (int o = 1; o < 1024; o <<= 1) {
    int v = (t >= o) ? part[t - o] : 0;
    __syncthreads();
    part[t] += v;
    __syncthreads();
  }
  int run = (t == 0) ? 0 : part[t - 1];
#pragma unroll
  for (int i = 0; i < 10; ++i) {
    int idx = base + i;
    if (idx < NNODES) { rowptr[idx] = run; cursor[idx] = run; run += cnt[idx]; }
  }
  if (t == 1023) rowptr[NNODES] = run;
}

// ---------------- fill + t + b2 + ef permute (one edge pass) -----------------
// For real edge e: pos = CSR slot. Dense reads; scattered writes at pos.
// Everything downstream (conv, attn) then streams dense CSR-ordered rows.
__global__ void __launch_bounds__(256) fill_t_kernel(
    const int* __restrict__ dst, const int* __restrict__ src,
    const float* __restrict__ f, const float* __restrict__ b1,
    const float* __restrict__ b2, const float* __restrict__ ef,
    int* __restrict__ cursor,
    u16* __restrict__ tbuf, float* __restrict__ b2p, u16* __restrict__ efp) {
  int e = blockIdx.x * 256 + threadIdx.x;        // grid exact
  int pos = atomicAdd(&cursor[dst[e]], 1);
  // t row: t[m,l] = sum_d f[src][m][d] * b1[e][d][l]
  const float* frow = f + (size_t)src[e] * 64;
  const float* be = b1 + (size_t)e * 8;          // (4,2)
  float b[8];
#pragma unroll
  for (int k = 0; k < 8; ++k) b[k] = be[k];
  uint4* tp = (uint4*)(tbuf + (size_t)pos * 32);
#pragma unroll
  for (int mh = 0; mh < 4; ++mh) {
    unsigned pk[4];
#pragma unroll
    for (int mi = 0; mi < 4; ++mi) {
      int m = mh * 4 + mi;
      float f0 = frow[m * 4 + 0], f1 = frow[m * 4 + 1], f2 = frow[m * 4 + 2], f3 = frow[m * 4 + 3];
      float t0 = f0 * b[0] + f1 * b[2] + f2 * b[4] + f3 * b[6];
      float t1 = f0 * b[1] + f1 * b[3] + f2 * b[5] + f3 * b[7];
      pk[mi] = pack_bf16(t0, t1);
    }
    tp[mh] = make_uint4(pk[0], pk[1], pk[2], pk[3]);
  }
  // b2 permuted copy
  const float* b2e = b2 + (size_t)e * 8;
  float* bp = b2p + (size_t)pos * 8;
  *(float4*)&bp[0] = *(const float4*)&b2e[0];
  *(float4*)&bp[4] = *(const float4*)&b2e[4];
  // ef permuted bf16 cast (32 elems -> 4 uint4)
  const float* efe = ef + (size_t)e * 32;
  uint4* ep = (uint4*)(efp + (size_t)pos * 32);
#pragma unroll
  for (int g = 0; g < 4; ++g) {
    float4 v0 = *(const float4*)&efe[g * 8];
    float4 v1 = *(const float4*)&efe[g * 8 + 4];
    ep[g] = make_uint4(pack_bf16(v0.x, v0.y), pack_bf16(v0.z, v0.w),
                       pack_bf16(v1.x, v1.y), pack_bf16(v1.z, v1.w));
  }
}

// ---------------- fused equivariant conv (transposed GEMMs) -----------------
// Per 64-edge block (512 threads = 8 waves):
//  h-stage: H^T = w1^T @ ef^T, B-frags DIRECT from global (dense CSR rows);
//           acc seeded with b1h bias; gelu; packed b64 writes into sA
//  K-loop : right = wr^T@H^T, left = wl^T@H^T; acc seeded with br/bl
//  epilogues: in-register rank contractions + 2/1 shuffles per tile
__global__ void __launch_bounds__(512) conv_fused_kernel(
    const u16* __restrict__ efp, const u16* __restrict__ w1sw,
    const float* __restrict__ b1h,
    const u16* __restrict__ wsw_r, const float* __restrict__ br,
    const u16* __restrict__ wsw_l, const float* __restrict__ bl,
    const u16* __restrict__ tbuf, const float* __restrict__ b2p,
    u16* __restrict__ kv) {
  __shared__ alignas(16) u16 sA[64 * 136];    // H tile [edge][hid]
  __shared__ alignas(16) u16 t_s[64 * 40];    // t tile (bf16)
  __shared__ alignas(16) float b2_s[64 * 12];
  __shared__ alignas(16) float u_s[64 * 12];  // u[e][p]
  __shared__ alignas(16) float t2_s[64 * 33]; // t2[e][r2], pitch 33 (bank+1)

  int tid = threadIdx.x;
  int wave = tid >> 6, lane = tid & 63, quad = lane >> 4, l16 = lane & 15;
  size_t i0 = (size_t)blockIdx.x * 64;

  // ---- stage t & b2 tiles ----
  if (tid < 256) {            // t tile: 64 rows x 32 u16
    int row = tid >> 2, seg = tid & 3;
    *(uint4*)&t_s[row * 40 + seg * 8] = *(const uint4*)&tbuf[(i0 + row) * 32 + seg * 8];
  } else if (tid < 384) {     // b2 tile: 64 rows x 8 f32
    int j = tid - 256, row = j >> 1, half = j & 1;
    *(float4*)&b2_s[row * 12 + half * 4] = *(const float4*)&b2p[(i0 + row) * 8 + half * 4];
  }

  // ---- h-stage: wave owns hid-tile `wave`; B-frags straight from global ----
  {
    bf16x8 aw = *(const bf16x8*)&w1sw[(size_t)(wave * 64 + lane) * 8];  // A = w1^T
    float4 bias_h = *(const float4*)&b1h[wave * 16 + quad * 4];
    f32x4 seed;
    seed[0] = bias_h.x; seed[1] = bias_h.y; seed[2] = bias_h.z; seed[3] = bias_h.w;
#pragma unroll
    for (int nt = 0; nt < 4; ++nt) {
      bf16x8 be = *(const bf16x8*)&efp[(i0 + nt * 16 + l16) * 32 + quad * 8]; // dense, coalesced
      f32x4 acch = __builtin_amdgcn_mfma_f32_16x16x32_bf16(aw, be, seed, 0, 0, 0);
      unsigned p0 = pack_bf16(fast_gelu(acch[0]), fast_gelu(acch[1]));
      unsigned p1 = pack_bf16(fast_gelu(acch[2]), fast_gelu(acch[3]));
      *(uint2*)&sA[(nt * 16 + l16) * 136 + wave * 16 + quad * 4] = make_uint2(p0, p1);
    }
  }
  __syncthreads();

  // ---- bias preloads & acc seeding: weight-col = (2w+mtl)*16 + 4q + r ----
  float4 brv[2], blv[2];
#pragma unroll
  for (int mtl = 0; mtl < 2; ++mtl) {
    int colb = (wave * 2 + mtl) * 16 + quad * 4;
    brv[mtl] = *(const float4*)&br[colb];
    blv[mtl] = *(const float4*)&bl[colb];
  }
  f32x4 accr[2][4], accl[2][4];
#pragma unroll
  for (int mtl = 0; mtl < 2; ++mtl)
#pragma unroll
    for (int nt = 0; nt < 4; ++nt) {
      accr[mtl][nt][0] = brv[mtl].x; accr[mtl][nt][1] = brv[mtl].y;
      accr[mtl][nt][2] = brv[mtl].z; accr[mtl][nt][3] = brv[mtl].w;
      accl[mtl][nt][0] = blv[mtl].x; accl[mtl][nt][1] = blv[mtl].y;
      accl[mtl][nt][2] = blv[mtl].z; accl[mtl][nt][3] = blv[mtl].w;
    }

  // ---- K-loop: transposed GEMMs (A = weights, B = H) ----
#pragma unroll
  for (int ks = 0; ks < 4; ++ks) {
    bf16x8 bfrag[4];
#pragma unroll
    for (int nt = 0; nt < 4; ++nt)
      bfrag[nt] = *(const bf16x8*)&sA[(nt * 16 + l16) * 136 + ks * 32 + quad * 8];
#pragma unroll
    for (int mtl = 0; mtl < 2; ++mtl) {
      int mtg = wave * 2 + mtl;
      bf16x8 ar = *(const bf16x8*)&wsw_r[(size_t)((mtg * 4 + ks) * 64 + lane) * 8];
      bf16x8 al = *(const bf16x8*)&wsw_l[(size_t)((mtg * 4 + ks) * 64 + lane) * 8];
#pragma unroll
      for (int nt = 0; nt < 4; ++nt) {
        accr[mtl][nt] = __builtin_amdgcn_mfma_f32_16x16x32_bf16(ar, bfrag[nt], accr[mtl][nt], 0, 0, 0);
        accl[mtl][nt] = __builtin_amdgcn_mfma_f32_16x16x32_bf16(al, bfrag[nt], accl[mtl][nt], 0, 0, 0);
      }
    }
  }

  // ---- right epilogue: u[e, p=wave] = sum_c right*t (bias pre-seeded) ----
#pragma unroll
  for (int nt = 0; nt < 4; ++nt) {
    int e = nt * 16 + l16;
    ushort4 ta = *(const ushort4*)&t_s[e * 40 + 4 * quad];        // c: mtl=0
    ushort4 tb = *(const ushort4*)&t_s[e * 40 + 16 + 4 * quad];   // c: mtl=1
    float s = accr[0][nt][0] * bf2f(ta.x)
            + accr[0][nt][1] * bf2f(ta.y)
            + accr[0][nt][2] * bf2f(ta.z)
            + accr[0][nt][3] * bf2f(ta.w)
            + accr[1][nt][0] * bf2f(tb.x)
            + accr[1][nt][1] * bf2f(tb.y)
            + accr[1][nt][2] * bf2f(tb.z)
            + accr[1][nt][3] * bf2f(tb.w);
    s += __shfl_xor(s, 16);
    s += __shfl_xor(s, 32);
    if (quad == 0) u_s[e * 12 + wave] = s;
  }
  __syncthreads();

  // ---- left epilogue: t2[e, r2] = sum_p left*u (bias pre-seeded) ----
#pragma unroll
  for (int nt = 0; nt < 4; ++nt) {
    int e = nt * 16 + l16;
    float4 uv = *(const float4*)&u_s[e * 12 + 4 * (quad & 1)];
#pragma unroll
    for (int mtl = 0; mtl < 2; ++mtl) {
      float s = accl[mtl][nt][0] * uv.x
              + accl[mtl][nt][1] * uv.y
              + accl[mtl][nt][2] * uv.z
              + accl[mtl][nt][3] * uv.w;
      s += __shfl_xor(s, 16);                    // combine p halves (q^1)
      if ((quad & 1) == 0)
        t2_s[e * 33 + 4 * wave + 2 * mtl + (quad >> 1)] = s;
    }
  }
  __syncthreads();

  // ---- kv stage: thread -> (e = tid>>3, j = tid&7) => elements j*8..j*8+7 ----
  {
    int e = tid >> 3, j = tid & 7;
    const float* tp = &t2_s[e * 33 + 4 * j];     // r2 = 4j..4j+3 (scalar reads, 2-way max)
    float t20 = tp[0], t21 = tp[1], t22 = tp[2], t23 = tp[3];
    float4 b2a = *(const float4*)&b2_s[e * 12 + 0];
    float4 b2b = *(const float4*)&b2_s[e * 12 + 4];
    unsigned q0 = pack_bf16(t20 * b2a.x + t21 * b2b.x, t20 * b2a.y + t21 * b2b.y);
    unsigned q1 = pack_bf16(t20 * b2a.z + t21 * b2b.z, t20 * b2a.w + t21 * b2b.w);
    unsigned q2 = pack_bf16(t22 * b2a.x + t23 * b2b.x, t22 * b2a.y + t23 * b2b.y);
    unsigned q3 = pack_bf16(t22 * b2a.z + t23 * b2b.z, t22 * b2a.w + t23 * b2b.w);
    *(uint4*)&kv[(i0 + e) * 64 + j * 8] = make_uint4(q0, q1, q2, q3);
  }
}

// ---------------- fused attention gather (streaming, DPP reduction) ---------
__global__ void __launch_bounds__(256) attn_gather_kernel(
    const float* __restrict__ q, const u16* __restrict__ kvk,
    const u16* __restrict__ kvv, const int* __restrict__ rowptr,
    float* __restrict__ outp) {
  int tid = threadIdx.x;
  int node = blockIdx.x * 4 + (tid >> 6);        // grid 2500 * 4 = NNODES
  int lane = tid & 63;
  float qv = q[(size_t)node * 64 + lane];
  int beg = rowptr[node], end = rowptr[node + 1];
  float num = 0.f, den = 0.f;
  for (int idx = beg; idx < end; ++idx) {        // contiguous rows (CSR order)
    float kf = bf2f(kvk[(size_t)idx * 64 + lane]);
    float p = dpp_red16(qv * kf);                // head-dot, pure VALU
    float exv = __expf(p * 0.25f);               // scale = sqrt(HM*DIM) = 4
    den += exv;
    num += exv * bf2f(kvv[(size_t)idx * 64 + lane]);
  }
  outp[(size_t)node * 64 + lane] = num / fmaxf(den, 1e-9f);
}

extern "C" void kernel_launch(void* const* d_in, const int* in_sizes, int n_in,
                              void* d_out, int out_size, void* d_ws, size_t ws_size,
                              hipStream_t stream) {
  const float* b1  = (const float*)d_in[0];
  const float* b2  = (const float*)d_in[1];
  const float* ef  = (const float*)d_in[2];
  const float* f   = (const float*)d_in[3];
  const int*   src = (const int*)d_in[4];
  const int*   dst = (const int*)d_in[5];
  const float* qw  = (const float*)d_in[6];
  const float* qb  = (const float*)d_in[7];
  const float* kw1 = (const float*)d_in[8];
  const float* kb1 = (const float*)d_in[9];
  const float* kwl = (const float*)d_in[10];
  const float* kbl = (const float*)d_in[11];
  const float* kwr = (const float*)d_in[12];
  const float* kbr = (const float*)d_in[13];
  const float* vw1 = (const float*)d_in[14];
  const float* vb1 = (const float*)d_in[15];
  const float* vwl = (const float*)d_in[16];
  const float* vbl = (const float*)d_in[17];
  const float* vwr = (const float*)d_in[18];
  const float* vbr = (const float*)d_in[19];
  float* outp = (float*)d_out;

  // workspace layout
  char* ws = (char*)d_ws;
  size_t off = 0;
  auto alloc = [&](size_t bytes) {
    char* p = ws + off;
    off += (bytes + 511) & ~(size_t)511;
    return p;
  };
  u16*   Wsw  = (u16*)  alloc((size_t)4 * 32768 * 2);
  u16*   W1sw = (u16*)  alloc((size_t)2 * 4096 * 2);
  u16*   tbuf = (u16*)  alloc((size_t)NEDGE * 32 * 2);
  float* b2p  = (float*)alloc((size_t)NEDGE * 8 * 4);
  u16*   efp  = (u16*)  alloc((size_t)NEDGE * 32 * 2);
  u16*   kvk  = (u16*)  alloc((size_t)NEDGE * 64 * 2);
  u16*   kvv  = (u16*)  alloc((size_t)NEDGE * 64 * 2);
  float* qbuf = (float*)alloc((size_t)NNODES * 64 * 4);
  int*   cnt    = (int*)alloc((size_t)NNODES * 4);
  int*   rowptr = (int*)alloc((size_t)(NNODES + 1) * 4);
  int*   cursor = (int*)alloc((size_t)NNODES * 4);

  // setup: csr_zero | prep_w | prep_w1 | q  (all independent)
  setup_kernel<<<1209, 256, 0, stream>>>(kwr, kwl, vwr, vwl, Wsw,
                                         kw1, vw1, W1sw,
                                         f, qw, qb, qbuf, cnt);
  // CSR build + edge-pass fusion (t, b2, ef all permuted to CSR order)
  csr_count_kernel<<<625, 256, 0, stream>>>(dst, cnt);
  csr_scan_kernel<<<1, 1024, 0, stream>>>(cnt, rowptr, cursor);
  fill_t_kernel<<<625, 256, 0, stream>>>(dst, src, f, b1, b2, ef,
                                         cursor, tbuf, b2p, efp);

  // conv K
  conv_fused_kernel<<<2500, 512, 0, stream>>>(efp, W1sw + 0 * 4096, kb1,
                                              Wsw + 0 * 32768, kbr,
                                              Wsw + 1 * 32768, kbl,
                                              tbuf, b2p, kvk);
  // conv V
  conv_fused_kernel<<<2500, 512, 0, stream>>>(efp, W1sw + 1 * 4096, vb1,
                                              Wsw + 2 * 32768, vbr,
                                              Wsw + 3 * 32768, vbl,
                                              tbuf, b2p, kvv);

  // fused attention (streaming reads, DPP reductions, no atomics)
  attn_gather_kernel<<<2500, 256, 0, stream>>>(qbuf, kvk, kvv, rowptr, outp);
}